// Round 1
// baseline (422.945 us; speedup 1.0000x reference)
//
#include <hip/hip_runtime.h>
#include <stdint.h>

#define AS_G __attribute__((address_space(1)))
#define AS_L __attribute__((address_space(3)))

typedef short bf16x8 __attribute__((ext_vector_type(8)));   // bits of 8 bf16
typedef float f32x4  __attribute__((ext_vector_type(4)));

// Problem constants (B=32, N=1024, D=512, H=8, DH=64)
constexpr int   M_ROWS = 32768;                    // B*N
constexpr float QSCALE = 0.18033688011112042f;     // log2(e) / sqrt(64)

__device__ __forceinline__ ushort f2bf(float f) {  // RTNE f32->bf16 (no NaN in data)
  uint32_t x = __float_as_uint(f);
  return (ushort)((x + 0x7fffu + ((x >> 16) & 1u)) >> 16);
}

__device__ __forceinline__ void gload16(const ushort* g, ushort* l) {
  // async global->LDS, 16B per lane; dest must be uniform_base + lane*16
  __builtin_amdgcn_global_load_lds((const AS_G uint32_t*)g, (AS_L uint32_t*)l, 16, 0, 0);
}

// ---------------- f32 -> bf16 convert (grid-stride, 8 elems/iter) ----------------
__global__ void cvt_bf16_kernel(const float* __restrict__ in,
                                ushort* __restrict__ out, int n8) {
  int stride = gridDim.x * blockDim.x;
  for (int i = blockIdx.x * blockDim.x + threadIdx.x; i < n8; i += stride) {
    float4 a = reinterpret_cast<const float4*>(in)[2 * i];
    float4 b = reinterpret_cast<const float4*>(in)[2 * i + 1];
    ushort4 o0 = {f2bf(a.x), f2bf(a.y), f2bf(a.z), f2bf(a.w)};
    ushort4 o1 = {f2bf(b.x), f2bf(b.y), f2bf(b.z), f2bf(b.w)};
    reinterpret_cast<ushort4*>(out)[2 * i]     = o0;
    reinterpret_cast<ushort4*>(out)[2 * i + 1] = o1;
  }
}

// ---------------- QKV projection GEMM: C = X @ W^T + bias, bf16 out ----------------
// 128x128 tile, BK=64, 4 waves (each 64x64), 16x16x32 bf16 MFMA.
// grid.x = 256 m-tiles * 12 (mat 0..2  x  4 n-tiles)
__global__ __launch_bounds__(256) void qkv_gemm_kernel(
    const ushort* __restrict__ Xb,    // [32768][512] bf16
    const ushort* __restrict__ Wall,  // [3][512][512] bf16 (q,k,v)
    const float* __restrict__ bq, const float* __restrict__ bk,
    const float* __restrict__ bv,
    ushort* __restrict__ QKV)         // [3][32768][512] bf16
{
  __shared__ ushort As[128 * 64];
  __shared__ ushort Bs[128 * 64];

  const int tile = blockIdx.x;
  const int mt  = tile & 255;
  const int cz  = tile >> 8;     // 0..11
  const int mat = cz >> 2;       // 0:q 1:k 2:v
  const int nt  = cz & 3;

  const ushort* W   = Wall + (size_t)mat * (512 * 512);
  const float*  bias = (mat == 0) ? bq : (mat == 1 ? bk : bv);
  ushort*       Out  = QKV + (size_t)mat * ((size_t)M_ROWS * 512);
  const float   oscale = (mat == 0) ? QSCALE : 1.0f;  // fold softmax scale into Q

  const int m0 = mt * 128, n0 = nt * 128;
  const int t = threadIdx.x, lane = t & 63, wave = t >> 6;
  const int wr = wave >> 1, wc = wave & 1;
  const int l15 = lane & 15, lg = lane >> 4;

  f32x4 acc[4][4];
#pragma unroll
  for (int i = 0; i < 4; i++)
#pragma unroll
    for (int j = 0; j < 4; j++) acc[i][j] = {0.f, 0.f, 0.f, 0.f};

  for (int kt = 0; kt < 8; ++kt) {
    const int k0 = kt * 64;
    __syncthreads();
#pragma unroll
    for (int i = 0; i < 4; ++i) {   // A tile: 128 rows x 64 cols
      int c = i * 256 + t, row = c >> 3, col8 = (c & 7) * 8;
      gload16(Xb + (size_t)(m0 + row) * 512 + k0 + col8, As + c * 8);
    }
#pragma unroll
    for (int i = 0; i < 4; ++i) {   // B tile: 128 n-rows of W x 64 k-cols
      int c = i * 256 + t, row = c >> 3, col8 = (c & 7) * 8;
      gload16(W + (size_t)(n0 + row) * 512 + k0 + col8, Bs + c * 8);
    }
    __syncthreads();                // drains vmcnt (loads landed in LDS)
#pragma unroll
    for (int ks = 0; ks < 2; ++ks) {
      bf16x8 af[4], bfr[4];
#pragma unroll
      for (int i = 0; i < 4; ++i) {
        af[i]  = *(const bf16x8*)(As + (wr * 64 + i * 16 + l15) * 64 + ks * 32 + lg * 8);
        bfr[i] = *(const bf16x8*)(Bs + (wc * 64 + i * 16 + l15) * 64 + ks * 32 + lg * 8);
      }
#pragma unroll
      for (int i = 0; i < 4; ++i)
#pragma unroll
        for (int j = 0; j < 4; ++j)
          acc[i][j] = __builtin_amdgcn_mfma_f32_16x16x32_bf16(af[i], bfr[j], acc[i][j], 0, 0, 0);
    }
  }
  // epilogue: +bias, (Q: *QSCALE), -> bf16
#pragma unroll
  for (int j = 0; j < 4; ++j) {
    const int col = n0 + wc * 64 + j * 16 + l15;
    const float bv_ = bias[col];
#pragma unroll
    for (int i = 0; i < 4; ++i) {
      const int row0 = m0 + wr * 64 + i * 16 + lg * 4;
#pragma unroll
      for (int r = 0; r < 4; ++r)
        Out[(size_t)(row0 + r) * 512 + col] = f2bf((acc[i][j][r] + bv_) * oscale);
    }
  }
}

// ---------------- flash attention, per (b,h): [1024x64] blocks ----------------
// grid.x = 256 bh * 16 q-blocks ; 4 waves, each owns 16 q-rows; KVBLK=64.
__global__ __launch_bounds__(256) void attn_kernel(
    const ushort* __restrict__ QKV,   // [3][256][1024][64] bf16 (Q pre-scaled)
    float* __restrict__ Out)          // [256][1024][64] f32
{
  constexpr int PLANE = M_ROWS * 512;  // elems per Q/K/V plane
  const int blk = blockIdx.x;
  const int bh = blk >> 4, qb = blk & 15;

  const ushort* Qg = QKV + (size_t)bh * 65536;
  const ushort* Kg = QKV + PLANE + (size_t)bh * 65536;
  const ushort* Vg = QKV + 2 * (size_t)PLANE + (size_t)bh * 65536;
  float* Og = Out + (size_t)bh * 65536;

  __shared__ ushort Ks[64 * 72];      // K tile, row-major, stride 72 (pad)
  __shared__ ushort Vts[64 * 72];     // V tile transposed: [d][m], stride 72
  __shared__ ushort Ps[4][16 * 72];   // per-wave P tile [16 q][64 m], stride 72

  const int t = threadIdx.x, lane = t & 63, wave = t >> 6;
  const int l15 = lane & 15, lg = lane >> 4;

  // Q fragments (A-layout: row=l15, k = ks*32 + lg*8 + j), held in regs
  const int qrow = qb * 64 + wave * 16 + l15;
  bf16x8 qf[2];
  qf[0] = *(const bf16x8*)(Qg + (size_t)qrow * 64 + lg * 8);
  qf[1] = *(const bf16x8*)(Qg + (size_t)qrow * 64 + 32 + lg * 8);

  float mrow[4], lrow[4];
#pragma unroll
  for (int j = 0; j < 4; j++) { mrow[j] = -1e30f; lrow[j] = 0.f; }
  f32x4 o[4];
#pragma unroll
  for (int d = 0; d < 4; d++) o[d] = {0.f, 0.f, 0.f, 0.f};

  for (int kv = 0; kv < 16; ++kv) {
    const ushort* Kt = Kg + kv * 4096;
    const ushort* Vt = Vg + kv * 4096;
    __syncthreads();
    // stage K tile (row-major, padded)
#pragma unroll
    for (int i = 0; i < 2; ++i) {
      int c = i * 256 + t, row = c >> 3, col8 = (c & 7) * 8;
      *(int4*)(Ks + row * 72 + col8) = *(const int4*)(Kt + row * 64 + col8);
    }
    // stage V transposed (scalar scatter)
#pragma unroll
    for (int i = 0; i < 2; ++i) {
      int c = i * 256 + t, row = c >> 3, col8 = (c & 7) * 8;
      ushort tmp[8];
      *(int4*)tmp = *(const int4*)(Vt + row * 64 + col8);
#pragma unroll
      for (int j = 0; j < 8; ++j) Vts[(col8 + j) * 72 + row] = tmp[j];
    }
    __syncthreads();

    // S = Q K^T  (logits already in exp2 domain; Q pre-scaled)
    f32x4 s[4];
#pragma unroll
    for (int mt_ = 0; mt_ < 4; ++mt_) {
      f32x4 a = {0.f, 0.f, 0.f, 0.f};
#pragma unroll
      for (int ks = 0; ks < 2; ++ks) {
        bf16x8 kf = *(const bf16x8*)(Ks + (mt_ * 16 + l15) * 72 + ks * 32 + lg * 8);
        a = __builtin_amdgcn_mfma_f32_16x16x32_bf16(qf[ks], kf, a, 0, 0, 0);
      }
      s[mt_] = a;
    }

    // online softmax (rows r = lg*4 + j; 16-lane butterfly over cols)
    float alpha[4], rsum[4];
#pragma unroll
    for (int j = 0; j < 4; ++j) {
      float v = fmaxf(fmaxf(s[0][j], s[1][j]), fmaxf(s[2][j], s[3][j]));
#pragma unroll
      for (int off = 8; off >= 1; off >>= 1) v = fmaxf(v, __shfl_xor(v, off));
      float mnew = fmaxf(mrow[j], v);
      alpha[j] = exp2f(mrow[j] - mnew);
      mrow[j] = mnew;
      rsum[j] = 0.f;
    }
#pragma unroll
    for (int mt_ = 0; mt_ < 4; ++mt_)
#pragma unroll
      for (int j = 0; j < 4; ++j) {
        float p = exp2f(s[mt_][j] - mrow[j]);
        s[mt_][j] = p;
        rsum[j] += p;
      }
#pragma unroll
    for (int j = 0; j < 4; ++j) {
      float v = rsum[j];
#pragma unroll
      for (int off = 8; off >= 1; off >>= 1) v += __shfl_xor(v, off);
      lrow[j] = lrow[j] * alpha[j] + v;
    }

    // P -> LDS (bf16), rescale O
    ushort* Pw = Ps[wave];
#pragma unroll
    for (int mt_ = 0; mt_ < 4; ++mt_)
#pragma unroll
      for (int j = 0; j < 4; ++j)
        Pw[(lg * 4 + j) * 72 + mt_ * 16 + l15] = f2bf(s[mt_][j]);
#pragma unroll
    for (int d = 0; d < 4; ++d)
#pragma unroll
      for (int j = 0; j < 4; ++j) o[d][j] *= alpha[j];

    // O += P V   (A-frag of P from per-wave LDS; B-frag of V from Vts)
#pragma unroll
    for (int ks = 0; ks < 2; ++ks) {
      bf16x8 pa = *(const bf16x8*)(Pw + l15 * 72 + ks * 32 + lg * 8);
#pragma unroll
      for (int d = 0; d < 4; ++d) {
        bf16x8 vf = *(const bf16x8*)(Vts + (d * 16 + l15) * 72 + ks * 32 + lg * 8);
        o[d] = __builtin_amdgcn_mfma_f32_16x16x32_bf16(pa, vf, o[d], 0, 0, 0);
      }
    }
  }

  // epilogue: divide by l, store f32
#pragma unroll
  for (int j = 0; j < 4; ++j) lrow[j] = 1.f / lrow[j];
#pragma unroll
  for (int d = 0; d < 4; ++d)
#pragma unroll
    for (int j = 0; j < 4; ++j)
      Og[(size_t)(qb * 64 + wave * 16 + lg * 4 + j) * 64 + d * 16 + l15] = o[d][j] * lrow[j];
}

// ---------------- launch ----------------
extern "C" void kernel_launch(void* const* d_in, const int* in_sizes, int n_in,
                              void* d_out, int out_size, void* d_ws, size_t ws_size,
                              hipStream_t stream) {
  (void)in_sizes; (void)n_in; (void)out_size; (void)ws_size;
  const float* x  = (const float*)d_in[0];
  const float* Wq = (const float*)d_in[1];
  const float* bq = (const float*)d_in[2];
  const float* Wk = (const float*)d_in[3];
  const float* bk = (const float*)d_in[4];
  const float* Wv = (const float*)d_in[5];
  const float* bv = (const float*)d_in[6];

  // ws layout (bytes): Xb[32M] | Wb[1.5M] | QKV[96M]
  ushort* Xb  = (ushort*)d_ws;                               // 32768*512 bf16
  ushort* Wb  = (ushort*)((char*)d_ws + 33554432);           // 3*512*512 bf16
  ushort* QKV = (ushort*)((char*)d_ws + 35127296);           // 3*32768*512 bf16

  cvt_bf16_kernel<<<2048, 256, 0, stream>>>(x, Xb, (32768 * 512) / 8);
  cvt_bf16_kernel<<<128, 256, 0, stream>>>(Wq, Wb + 0 * 262144, 262144 / 8);
  cvt_bf16_kernel<<<128, 256, 0, stream>>>(Wk, Wb + 1 * 262144, 262144 / 8);
  cvt_bf16_kernel<<<128, 256, 0, stream>>>(Wv, Wb + 2 * 262144, 262144 / 8);

  qkv_gemm_kernel<<<256 * 12, 256, 0, stream>>>(Xb, Wb, bq, bk, bv, QKV);

  attn_kernel<<<256 * 16, 256, 0, stream>>>(QKV, (float*)d_out);
}

// Round 3
// 290.713 us; speedup vs baseline: 1.4549x; 1.4549x over previous
//
#include <hip/hip_runtime.h>
#include <stdint.h>

#define AS_G __attribute__((address_space(1)))
#define AS_L __attribute__((address_space(3)))

typedef short bf16x8 __attribute__((ext_vector_type(8)));   // bits of 8 bf16
typedef float f32x4  __attribute__((ext_vector_type(4)));
typedef float f32x16 __attribute__((ext_vector_type(16)));

// Problem constants (B=32, N=1024, D=512, H=8, DH=64)
constexpr int   M_ROWS = 32768;                    // B*N
constexpr float QSCALE = 0.18033688011112042f;     // log2(e) / sqrt(64)

__device__ __forceinline__ ushort f2bf(float f) {  // RTNE f32->bf16
  uint32_t x = __float_as_uint(f);
  return (ushort)((x + 0x7fffu + ((x >> 16) & 1u)) >> 16);
}
__device__ __forceinline__ uint32_t pack2bf(float lo, float hi) {
  return (uint32_t)f2bf(lo) | ((uint32_t)f2bf(hi) << 16);
}
__device__ __forceinline__ void gload16(const ushort* g, ushort* l) {
  // async global->LDS, 16B/lane; LDS dest must be uniform_base + lane*16
  __builtin_amdgcn_global_load_lds((const AS_G uint32_t*)g, (AS_L uint32_t*)l, 16, 0, 0);
}

// ---------------- f32 -> bf16 convert ----------------
__global__ void cvt_bf16_kernel(const float* __restrict__ in,
                                ushort* __restrict__ out, int n8) {
  int stride = gridDim.x * blockDim.x;
  for (int i = blockIdx.x * blockDim.x + threadIdx.x; i < n8; i += stride) {
    float4 a = reinterpret_cast<const float4*>(in)[2 * i];
    float4 b = reinterpret_cast<const float4*>(in)[2 * i + 1];
    ushort4 o0 = {f2bf(a.x), f2bf(a.y), f2bf(a.z), f2bf(a.w)};
    ushort4 o1 = {f2bf(b.x), f2bf(b.y), f2bf(b.z), f2bf(b.w)};
    reinterpret_cast<ushort4*>(out)[2 * i]     = o0;
    reinterpret_cast<ushort4*>(out)[2 * i + 1] = o1;
  }
}

// ---------------- QKV projection GEMM (round-1, known-good) ----------------
// C = X @ W^T + bias -> bf16 plane [32768][512]; Q pre-scaled by QSCALE.
__global__ __launch_bounds__(256) void qkv_gemm_kernel(
    const ushort* __restrict__ Xb, const ushort* __restrict__ Wall,
    const float* __restrict__ bq, const float* __restrict__ bk,
    const float* __restrict__ bv,
    ushort* __restrict__ QKV)
{
  __shared__ ushort As[128 * 64];
  __shared__ ushort Bs[128 * 64];

  const int tile = blockIdx.x;
  const int mt  = tile & 255;
  const int cz  = tile >> 8;     // 0..11
  const int mat = cz >> 2;       // 0:q 1:k 2:v
  const int nt  = cz & 3;

  const ushort* W    = Wall + (size_t)mat * (512 * 512);
  const float*  bias = (mat == 0) ? bq : (mat == 1 ? bk : bv);
  ushort*       Out  = QKV + (size_t)mat * ((size_t)M_ROWS * 512);
  const float   oscale = (mat == 0) ? QSCALE : 1.0f;

  const int m0 = mt * 128, n0 = nt * 128;
  const int t = threadIdx.x, lane = t & 63, wave = t >> 6;
  const int wr = wave >> 1, wc = wave & 1;
  const int l15 = lane & 15, lg = lane >> 4;

  f32x4 acc[4][4];
#pragma unroll
  for (int i = 0; i < 4; i++)
#pragma unroll
    for (int j = 0; j < 4; j++) acc[i][j] = {0.f, 0.f, 0.f, 0.f};

  for (int kt = 0; kt < 8; ++kt) {
    const int k0 = kt * 64;
    __syncthreads();
#pragma unroll
    for (int i = 0; i < 4; ++i) {
      int c = i * 256 + t, row = c >> 3, col8 = (c & 7) * 8;
      gload16(Xb + (size_t)(m0 + row) * 512 + k0 + col8, As + c * 8);
    }
#pragma unroll
    for (int i = 0; i < 4; ++i) {
      int c = i * 256 + t, row = c >> 3, col8 = (c & 7) * 8;
      gload16(W + (size_t)(n0 + row) * 512 + k0 + col8, Bs + c * 8);
    }
    __syncthreads();
#pragma unroll
    for (int ks = 0; ks < 2; ++ks) {
      bf16x8 af[4], bfr[4];
#pragma unroll
      for (int i = 0; i < 4; ++i) {
        af[i]  = *(const bf16x8*)(As + (wr * 64 + i * 16 + l15) * 64 + ks * 32 + lg * 8);
        bfr[i] = *(const bf16x8*)(Bs + (wc * 64 + i * 16 + l15) * 64 + ks * 32 + lg * 8);
      }
#pragma unroll
      for (int i = 0; i < 4; ++i)
#pragma unroll
        for (int j = 0; j < 4; ++j)
          acc[i][j] = __builtin_amdgcn_mfma_f32_16x16x32_bf16(af[i], bfr[j], acc[i][j], 0, 0, 0);
    }
  }
#pragma unroll
  for (int j = 0; j < 4; ++j) {
    const int col = n0 + wc * 64 + j * 16 + l15;
    const float bc = bias[col];
#pragma unroll
    for (int i = 0; i < 4; ++i) {
      const int row0 = m0 + wr * 64 + i * 16 + lg * 4;
#pragma unroll
      for (int r = 0; r < 4; ++r)
        Out[(size_t)(row0 + r) * 512 + col] = f2bf((acc[i][j][r] + bc) * oscale);
    }
  }
}

// ---------------- V transpose: VT[bh][dh][n] = flatV[bh*65536 + n*64 + dh] ---
// (raw-reshape aliasing of the natural V plane). grid = 256 bh * 4 n-chunks.
__global__ __launch_bounds__(256) void vtrans_kernel(
    const ushort* __restrict__ Vn, ushort* __restrict__ VT)
{
  __shared__ ushort T[64][258];   // [dh][n-local], padded stride
  const int bh = blockIdx.x >> 2, nc = blockIdx.x & 3;
  const ushort* src = Vn + (size_t)bh * 65536 + nc * 16384;
  ushort* dst = VT + (size_t)bh * 65536 + nc * 256;
  const int t = threadIdx.x;
#pragma unroll
  for (int i = 0; i < 8; ++i) {   // load [256 n][64 dh], scatter-transpose
    int c = i * 256 + t, n = c >> 3, col8 = (c & 7) * 8;
    ushort tmp[8];
    *(int4*)tmp = *(const int4*)(src + n * 64 + col8);
#pragma unroll
    for (int j = 0; j < 8; ++j) T[col8 + j][n] = tmp[j];
  }
  __syncthreads();
#pragma unroll
  for (int i = 0; i < 8; ++i) {   // write [64 dh][256 n] coalesced
    int c = i * 256 + t, dh = c >> 5, a8 = (c & 31) * 8;
    *(int4*)(dst + (size_t)dh * 1024 + a8) = *(const int4*)(&T[dh][a8]);
  }
}

// ---------------- flash attention: 4 waves x 32 q-rows, KVBLK=64, 32x32x16 ----
// grid = 256 bh * 8 q-blocks. Swapped QK^T (S^T = K Q^T) -> lane-local softmax;
// P exchanged in-register (pack + shfl_xor 32); PV as O^T = V^T P^T.
__global__ __launch_bounds__(256) void attn_kernel(
    const ushort* __restrict__ QKV,   // planes: Q[bh][n][64], K[bh][n][64]
    const ushort* __restrict__ VTg_,  // V^T [bh][64 dh][1024 n]
    float* __restrict__ Out)          // [bh][1024][64] f32
{
  constexpr int PLANE = M_ROWS * 512;
  __shared__ ushort SMEM[64 * 258];          // 33024 B: staging + out-transpose
  ushort* sK = SMEM;                          // [2][4096]
  ushort* sV = SMEM + 8192;                   // [2][4096]
  float* Lbuf = (float*)SMEM;                 // epilogue alias [64][129]

  const int blk = blockIdx.x;
  const int bh = blk >> 3, qb = blk & 7;
  const ushort* Qg  = QKV + (size_t)bh * 65536;
  const ushort* Kg  = QKV + (size_t)PLANE + (size_t)bh * 65536;
  const ushort* Vtg = VTg_ + (size_t)bh * 65536;

  const int t = threadIdx.x, lane = t & 63, wave = t >> 6;
  const int l31 = lane & 31, h = lane >> 5;
  const int q = qb * 128 + wave * 32 + l31;

  bf16x8 qf[4];
#pragma unroll
  for (int ks = 0; ks < 4; ++ks)
    qf[ks] = *(const bf16x8*)(Qg + (size_t)q * 64 + ks * 16 + h * 8);

  float mrow = -1e30f, lrow = 0.f;
  f32x16 o[2];
#pragma unroll
  for (int r = 0; r < 16; ++r) { o[0][r] = 0.f; o[1][r] = 0.f; }

  // prologue stage (tile 0)
#pragma unroll
  for (int i = 0; i < 2; ++i) {
    int c = i * 256 + t, row = c >> 3, slot = c & 7;
    gload16(Kg + (size_t)row * 64 + ((slot ^ (row & 7)) << 3), sK + c * 8);
    gload16(Vtg + (size_t)row * 1024 + ((slot ^ (row & 7)) << 3), sV + c * 8);
  }
  __syncthreads();

  for (int kv = 0; kv < 16; ++kv) {
    const int cur = kv & 1;
    if (kv < 15) {
      const int nx = cur ^ 1, kn = kv + 1;
#pragma unroll
      for (int i = 0; i < 2; ++i) {
        int c = i * 256 + t, row = c >> 3, slot = c & 7;
        gload16(Kg + (size_t)(kn * 64 + row) * 64 + ((slot ^ (row & 7)) << 3),
                sK + nx * 4096 + c * 8);
        gload16(Vtg + (size_t)row * 1024 + kn * 64 + ((slot ^ (row & 7)) << 3),
                sV + nx * 4096 + c * 8);
      }
    }
    const ushort* Kc = sK + cur * 4096;
    const ushort* Vc = sV + cur * 4096;

    // S^T = K Q^T : lane holds S[k = tt*32 + (r&3)+8*(r>>2)+4h][q = l31]
    f32x16 st[2];
#pragma unroll
    for (int tt = 0; tt < 2; ++tt) {
      f32x16 a;
#pragma unroll
      for (int r = 0; r < 16; ++r) a[r] = 0.f;
#pragma unroll
      for (int ks = 0; ks < 4; ++ks) {
        const int krow = tt * 32 + l31;
        bf16x8 kf = *(const bf16x8*)(Kc + krow * 64 + (((ks * 2 + h) ^ (krow & 7)) << 3));
        a = __builtin_amdgcn_mfma_f32_32x32x16_bf16(kf, qf[ks], a, 0, 0, 0);
      }
      st[tt] = a;
    }

    // online softmax (row = q = l31, lane-local + one xor-32)
    float mx = st[0][0];
#pragma unroll
    for (int r = 1; r < 16; ++r) mx = fmaxf(mx, st[0][r]);
#pragma unroll
    for (int r = 0; r < 16; ++r) mx = fmaxf(mx, st[1][r]);
    mx = fmaxf(mx, __shfl_xor(mx, 32));
    const float mnew = fmaxf(mrow, mx);
    const float alpha = exp2f(mrow - mnew);
    mrow = mnew;
    float rs = 0.f;
#pragma unroll
    for (int tt = 0; tt < 2; ++tt)
#pragma unroll
      for (int r = 0; r < 16; ++r) {
        float p = exp2f(st[tt][r] - mnew);
        st[tt][r] = p;
        rs += p;
      }
    rs += __shfl_xor(rs, 32);
    lrow = lrow * alpha + rs;
#pragma unroll
    for (int r = 0; r < 16; ++r) { o[0][r] *= alpha; o[1][r] *= alpha; }

    // P -> bf16 B-frags in-register; O^T += V^T P^T
#pragma unroll
    for (int tt = 0; tt < 2; ++tt) {
      uint32_t U[8];
#pragma unroll
      for (int p = 0; p < 8; ++p) U[p] = pack2bf(st[tt][2 * p], st[tt][2 * p + 1]);
      uint32_t R[2][2];
#pragma unroll
      for (int s = 0; s < 2; ++s)
#pragma unroll
        for (int i = 0; i < 2; ++i)
          R[s][i] = (uint32_t)__shfl_xor((int)(h ? U[4 * s + i] : U[4 * s + 2 + i]), 32);
#pragma unroll
      for (int s = 0; s < 2; ++s) {
        const int ks2 = tt * 2 + s;
        union { uint32_t u[4]; bf16x8 v; } pf;
        if (h == 0) {
          pf.u[0] = U[4 * s];     pf.u[1] = U[4 * s + 1];
          pf.u[2] = R[s][0];      pf.u[3] = R[s][1];
        } else {
          pf.u[0] = R[s][0];      pf.u[1] = R[s][1];
          pf.u[2] = U[4 * s + 2]; pf.u[3] = U[4 * s + 3];
        }
#pragma unroll
        for (int dt = 0; dt < 2; ++dt) {
          const int drow = dt * 32 + l31;
          bf16x8 vf = *(const bf16x8*)(Vc + drow * 64 + (((ks2 * 2 + h) ^ (drow & 7)) << 3));
          o[dt] = __builtin_amdgcn_mfma_f32_32x32x16_bf16(vf, pf.v, o[dt], 0, 0, 0);
        }
      }
    }
    __syncthreads();
  }

  // epilogue: O^T (lane: q=l31, rows=d) -> LDS -> coalesced [q][d] f32 stores
  const float linv = 1.f / lrow;
#pragma unroll
  for (int dt = 0; dt < 2; ++dt)
#pragma unroll
    for (int r = 0; r < 16; ++r) {
      const int d = dt * 32 + (r & 3) + 8 * (r >> 2) + 4 * h;
      Lbuf[d * 129 + wave * 32 + l31] = o[dt][r] * linv;
    }
  __syncthreads();
  {
    const int qloc = t >> 1, dh = (t & 1) * 32;
    float* ob = Out + (size_t)bh * 65536 + (size_t)(qb * 128 + qloc) * 64 + dh;
#pragma unroll
    for (int c = 0; c < 8; ++c) {
      float4 v = { Lbuf[(dh + 4 * c + 0) * 129 + qloc],
                   Lbuf[(dh + 4 * c + 1) * 129 + qloc],
                   Lbuf[(dh + 4 * c + 2) * 129 + qloc],
                   Lbuf[(dh + 4 * c + 3) * 129 + qloc] };
      *(float4*)(ob + 4 * c) = v;
    }
  }
}

// ---------------- launch ----------------
extern "C" void kernel_launch(void* const* d_in, const int* in_sizes, int n_in,
                              void* d_out, int out_size, void* d_ws, size_t ws_size,
                              hipStream_t stream) {
  (void)in_sizes; (void)n_in; (void)out_size; (void)ws_size;
  const float* x  = (const float*)d_in[0];
  const float* Wq = (const float*)d_in[1];
  const float* bq = (const float*)d_in[2];
  const float* Wk = (const float*)d_in[3];
  const float* bk = (const float*)d_in[4];
  const float* Wv = (const float*)d_in[5];
  const float* bv = (const float*)d_in[6];

  // ws layout (bytes): Xb/VT[32M] | Wb[1.5M] | QKV[96M]
  // Xb is dead after the GEMM; VT reuses its region.
  ushort* Xb  = (ushort*)d_ws;
  ushort* VT  = (ushort*)d_ws;
  ushort* Wb  = (ushort*)((char*)d_ws + 33554432);
  ushort* QKV = (ushort*)((char*)d_ws + 35127296);
  ushort* Vn  = QKV + 2 * (size_t)M_ROWS * 512;   // natural V plane

  cvt_bf16_kernel<<<2048, 256, 0, stream>>>(x, Xb, (32768 * 512) / 8);
  cvt_bf16_kernel<<<128, 256, 0, stream>>>(Wq, Wb + 0 * 262144, 262144 / 8);
  cvt_bf16_kernel<<<128, 256, 0, stream>>>(Wk, Wb + 1 * 262144, 262144 / 8);
  cvt_bf16_kernel<<<128, 256, 0, stream>>>(Wv, Wb + 2 * 262144, 262144 / 8);

  qkv_gemm_kernel<<<256 * 12, 256, 0, stream>>>(Xb, Wb, bq, bk, bv, QKV);

  vtrans_kernel<<<1024, 256, 0, stream>>>(Vn, VT);

  attn_kernel<<<256 * 8, 256, 0, stream>>>(QKV, VT, (float*)d_out);
}

// Round 4
// 248.736 us; speedup vs baseline: 1.7004x; 1.1688x over previous
//
#include <hip/hip_runtime.h>
#include <hip/hip_bf16.h>
#include <stdint.h>

#define AS_G __attribute__((address_space(1)))
#define AS_L __attribute__((address_space(3)))

typedef short bf16x8 __attribute__((ext_vector_type(8)));   // bits of 8 bf16
typedef float f32x4  __attribute__((ext_vector_type(4)));
typedef float f32x16 __attribute__((ext_vector_type(16)));

// Problem constants (B=32, N=1024, D=512, H=8, DH=64)
constexpr int   M_ROWS = 32768;                    // B*N
constexpr float QSCALE = 0.18033688011112042f;     // log2(e) / sqrt(64)

__device__ __forceinline__ ushort f2bf(float f) {  // hw RTNE f32->bf16
  union { __hip_bfloat16 h; ushort u; } c;
  c.h = __float2bfloat16(f);
  return c.u;
}
__device__ __forceinline__ uint32_t pack2bf(float lo, float hi) {
  union { __hip_bfloat162 b; uint32_t u; } r;
  r.b.x = __float2bfloat16(lo);
  r.b.y = __float2bfloat16(hi);
  return r.u;
}
__device__ __forceinline__ void gload16(const ushort* g, ushort* l) {
  // async global->LDS, 16B/lane; LDS dest must be uniform_base + lane*16
  __builtin_amdgcn_global_load_lds((const AS_G uint32_t*)g, (AS_L uint32_t*)l, 16, 0, 0);
}

// ---------------- f32 -> bf16 convert (x + 3 W in one launch) ----------------
__device__ __forceinline__ void cvt8(const float* __restrict__ in,
                                     ushort* __restrict__ out, int i) {
  float4 a = reinterpret_cast<const float4*>(in)[2 * i];
  float4 b = reinterpret_cast<const float4*>(in)[2 * i + 1];
  ushort4 o0 = {f2bf(a.x), f2bf(a.y), f2bf(a.z), f2bf(a.w)};
  ushort4 o1 = {f2bf(b.x), f2bf(b.y), f2bf(b.z), f2bf(b.w)};
  reinterpret_cast<ushort4*>(out)[2 * i]     = o0;
  reinterpret_cast<ushort4*>(out)[2 * i + 1] = o1;
}

__global__ __launch_bounds__(256) void cvt_all_kernel(
    const float* __restrict__ x,  const float* __restrict__ wq,
    const float* __restrict__ wk, const float* __restrict__ wv,
    ushort* __restrict__ xb, ushort* __restrict__ wb) {
  const int b = blockIdx.x, t = threadIdx.x;
  if (b < 2048) {                 // x: 2,097,152 groups = 2048*256*4
    const int i0 = b * 256 + t;
#pragma unroll
    for (int rep = 0; rep < 4; ++rep) cvt8(x, xb, i0 + rep * 524288);
  } else {                        // W: 3 mats x 32768 groups (128 blocks each)
    const int c = b - 2048, m = c >> 7;
    const float* src = (m == 0) ? wq : (m == 1 ? wk : wv);
    cvt8(src, wb + m * 262144, (c & 127) * 256 + t);
  }
}

// ---------------- QKV projection GEMM (round-1 structure, known-good) --------
// C = X @ W^T + bias -> bf16 plane [32768][512]; Q pre-scaled by QSCALE.
__global__ __launch_bounds__(256) void qkv_gemm_kernel(
    const ushort* __restrict__ Xb, const ushort* __restrict__ Wall,
    const float* __restrict__ bq, const float* __restrict__ bk,
    const float* __restrict__ bv,
    ushort* __restrict__ QKV)
{
  __shared__ ushort As[128 * 64];
  __shared__ ushort Bs[128 * 64];

  const int tile = blockIdx.x;
  const int mt  = tile & 255;
  const int cz  = tile >> 8;     // 0..11
  const int mat = cz >> 2;       // 0:q 1:k 2:v
  const int nt  = cz & 3;

  const ushort* W    = Wall + (size_t)mat * (512 * 512);
  const float*  bias = (mat == 0) ? bq : (mat == 1 ? bk : bv);
  ushort*       Out  = QKV + (size_t)mat * ((size_t)M_ROWS * 512);
  const float   oscale = (mat == 0) ? QSCALE : 1.0f;

  const int m0 = mt * 128, n0 = nt * 128;
  const int t = threadIdx.x, lane = t & 63, wave = t >> 6;
  const int wr = wave >> 1, wc = wave & 1;
  const int l15 = lane & 15, lg = lane >> 4;

  f32x4 acc[4][4];
#pragma unroll
  for (int i = 0; i < 4; i++)
#pragma unroll
    for (int j = 0; j < 4; j++) acc[i][j] = {0.f, 0.f, 0.f, 0.f};

  for (int kt = 0; kt < 8; ++kt) {
    const int k0 = kt * 64;
    __syncthreads();
#pragma unroll
    for (int i = 0; i < 4; ++i) {
      int c = i * 256 + t, row = c >> 3, col8 = (c & 7) * 8;
      gload16(Xb + (size_t)(m0 + row) * 512 + k0 + col8, As + c * 8);
    }
#pragma unroll
    for (int i = 0; i < 4; ++i) {
      int c = i * 256 + t, row = c >> 3, col8 = (c & 7) * 8;
      gload16(W + (size_t)(n0 + row) * 512 + k0 + col8, Bs + c * 8);
    }
    __syncthreads();
#pragma unroll
    for (int ks = 0; ks < 2; ++ks) {
      bf16x8 af[4], bfr[4];
#pragma unroll
      for (int i = 0; i < 4; ++i) {
        af[i]  = *(const bf16x8*)(As + (wr * 64 + i * 16 + l15) * 64 + ks * 32 + lg * 8);
        bfr[i] = *(const bf16x8*)(Bs + (wc * 64 + i * 16 + l15) * 64 + ks * 32 + lg * 8);
      }
#pragma unroll
      for (int i = 0; i < 4; ++i)
#pragma unroll
        for (int j = 0; j < 4; ++j)
          acc[i][j] = __builtin_amdgcn_mfma_f32_16x16x32_bf16(af[i], bfr[j], acc[i][j], 0, 0, 0);
    }
  }
#pragma unroll
  for (int j = 0; j < 4; ++j) {
    const int col = n0 + wc * 64 + j * 16 + l15;
    const float bc = bias[col];
#pragma unroll
    for (int i = 0; i < 4; ++i) {
      const int row0 = m0 + wr * 64 + i * 16 + lg * 4;
#pragma unroll
      for (int r = 0; r < 4; ++r)
        Out[(size_t)(row0 + r) * 512 + col] = f2bf((acc[i][j][r] + bc) * oscale);
    }
  }
}

// ---------------- V transpose: VT[bh][dh][n] = flatV[bh*65536 + n*64 + dh] ---
__global__ __launch_bounds__(256) void vtrans_kernel(
    const ushort* __restrict__ Vn, ushort* __restrict__ VT)
{
  __shared__ ushort T[64][258];   // [dh][n-local], padded stride
  const int bh = blockIdx.x >> 2, nc = blockIdx.x & 3;
  const ushort* src = Vn + (size_t)bh * 65536 + nc * 16384;
  ushort* dst = VT + (size_t)bh * 65536 + nc * 256;
  const int t = threadIdx.x;
#pragma unroll
  for (int i = 0; i < 8; ++i) {   // load [256 n][64 dh], scatter-transpose
    int c = i * 256 + t, n = c >> 3, col8 = (c & 7) * 8;
    ushort tmp[8];
    *(int4*)tmp = *(const int4*)(src + n * 64 + col8);
#pragma unroll
    for (int j = 0; j < 8; ++j) T[col8 + j][n] = tmp[j];
  }
  __syncthreads();
#pragma unroll
  for (int i = 0; i < 8; ++i) {   // write [64 dh][256 n] coalesced
    int c = i * 256 + t, dh = c >> 5, a8 = (c & 31) * 8;
    *(int4*)(dst + (size_t)dh * 1024 + a8) = *(const int4*)(&T[dh][a8]);
  }
}

// ---------------- flash attention: 4 waves x 32 q-rows, KVBLK=64, 32x32x16 ----
// grid = 256 bh * 8 q-blocks. Swapped QK^T (S^T = K Q^T) -> lane-local softmax;
// P exchanged in-register (pack + shfl_xor 32); PV as O^T = V^T P^T.
// Defer-max (THR=8 in log2 units) skips the O-rescale on flat tiles.
__global__ __launch_bounds__(256, 4) void attn_kernel(
    const ushort* __restrict__ QKV,   // planes: Q[bh][n][64], K[bh][n][64]
    const ushort* __restrict__ VTg_,  // V^T [bh][64 dh][1024 n]
    float* __restrict__ Out)          // [bh][1024][64] f32
{
  constexpr int PLANE = M_ROWS * 512;
  __shared__ ushort SMEM[64 * 258];          // 33024 B: staging + out-transpose
  ushort* sK = SMEM;                          // [2][4096]
  ushort* sV = SMEM + 8192;                   // [2][4096]
  float* Lbuf = (float*)SMEM;                 // epilogue alias [64][129]

  const int blk = blockIdx.x;
  const int bh = blk >> 3, qb = blk & 7;
  const ushort* Qg  = QKV + (size_t)bh * 65536;
  const ushort* Kg  = QKV + (size_t)PLANE + (size_t)bh * 65536;
  const ushort* Vtg = VTg_ + (size_t)bh * 65536;

  const int t = threadIdx.x, lane = t & 63, wave = t >> 6;
  const int l31 = lane & 31, h = lane >> 5;
  const int q = qb * 128 + wave * 32 + l31;

  bf16x8 qf[4];
#pragma unroll
  for (int ks = 0; ks < 4; ++ks)
    qf[ks] = *(const bf16x8*)(Qg + (size_t)q * 64 + ks * 16 + h * 8);

  // per-lane swizzled LDS read offsets (ushort units); same table for K and V
  int off[2][4];
#pragma unroll
  for (int tt = 0; tt < 2; ++tt) {
    const int row = tt * 32 + l31;
#pragma unroll
    for (int ks = 0; ks < 4; ++ks)
      off[tt][ks] = row * 64 + (((ks * 2 + h) ^ (row & 7)) << 3);
  }

  float mrow = -1e30f, lrow = 0.f;
  f32x16 o[2];
#pragma unroll
  for (int r = 0; r < 16; ++r) { o[0][r] = 0.f; o[1][r] = 0.f; }

  // prologue stage (tile 0)
#pragma unroll
  for (int i = 0; i < 2; ++i) {
    int c = i * 256 + t, row = c >> 3, slot = c & 7;
    gload16(Kg + (size_t)row * 64 + ((slot ^ (row & 7)) << 3), sK + c * 8);
    gload16(Vtg + (size_t)row * 1024 + ((slot ^ (row & 7)) << 3), sV + c * 8);
  }
  __syncthreads();

  for (int kv = 0; kv < 16; ++kv) {
    const int cur = kv & 1;
    if (kv < 15) {
      const int nx = cur ^ 1, kn = kv + 1;
#pragma unroll
      for (int i = 0; i < 2; ++i) {
        int c = i * 256 + t, row = c >> 3, slot = c & 7;
        gload16(Kg + (size_t)(kn * 64 + row) * 64 + ((slot ^ (row & 7)) << 3),
                sK + nx * 4096 + c * 8);
        gload16(Vtg + (size_t)row * 1024 + kn * 64 + ((slot ^ (row & 7)) << 3),
                sV + nx * 4096 + c * 8);
      }
    }
    const ushort* Kc = sK + cur * 4096;
    const ushort* Vc = sV + cur * 4096;

    // S^T = K Q^T : lane holds S[k = tt*32 + (r&3)+8*(r>>2)+4h][q = l31]
    f32x16 st[2];
#pragma unroll
    for (int tt = 0; tt < 2; ++tt) {
      f32x16 a;
#pragma unroll
      for (int r = 0; r < 16; ++r) a[r] = 0.f;
#pragma unroll
      for (int ks = 0; ks < 4; ++ks) {
        bf16x8 kf = *(const bf16x8*)(Kc + off[tt][ks]);
        a = __builtin_amdgcn_mfma_f32_32x32x16_bf16(kf, qf[ks], a, 0, 0, 0);
      }
      st[tt] = a;
    }

    // online softmax (row = q = l31): tree max, defer-max rescale
    float mx;
    {
      float t8[8];
#pragma unroll
      for (int i = 0; i < 8; ++i)
        t8[i] = fmaxf(fmaxf(st[0][i], st[0][i + 8]), fmaxf(st[1][i], st[1][i + 8]));
      float a0 = fmaxf(fmaxf(t8[0], t8[1]), fmaxf(t8[2], t8[3]));
      float a1 = fmaxf(fmaxf(t8[4], t8[5]), fmaxf(t8[6], t8[7]));
      mx = fmaxf(a0, a1);
    }
    mx = fmaxf(mx, __shfl_xor(mx, 32));
    if (!__all(mx - mrow <= 8.0f)) {       // rescale path (rare after tile 0)
      const float mnew = fmaxf(mrow, mx);
      const float alpha = exp2f(mrow - mnew);
      mrow = mnew;
      lrow *= alpha;
#pragma unroll
      for (int r = 0; r < 16; ++r) { o[0][r] *= alpha; o[1][r] *= alpha; }
    }
#pragma unroll
    for (int tt = 0; tt < 2; ++tt)
#pragma unroll
      for (int r = 0; r < 16; ++r) st[tt][r] = exp2f(st[tt][r] - mrow);
    {
      float s8[8];
#pragma unroll
      for (int i = 0; i < 8; ++i)
        s8[i] = (st[0][i] + st[0][i + 8]) + (st[1][i] + st[1][i + 8]);
      float rs = ((s8[0] + s8[1]) + (s8[2] + s8[3]))
               + ((s8[4] + s8[5]) + (s8[6] + s8[7]));
      rs += __shfl_xor(rs, 32);
      lrow += rs;
    }

    // P -> bf16 B-frags in-register; O^T += V^T P^T
#pragma unroll
    for (int tt = 0; tt < 2; ++tt) {
      uint32_t U[8];
#pragma unroll
      for (int p = 0; p < 8; ++p) U[p] = pack2bf(st[tt][2 * p], st[tt][2 * p + 1]);
      uint32_t R[2][2];
#pragma unroll
      for (int s = 0; s < 2; ++s)
#pragma unroll
        for (int i = 0; i < 2; ++i)
          R[s][i] = (uint32_t)__shfl_xor((int)(h ? U[4 * s + i] : U[4 * s + 2 + i]), 32);
#pragma unroll
      for (int s = 0; s < 2; ++s) {
        union { uint32_t u[4]; bf16x8 v; } pf;
        if (h == 0) {
          pf.u[0] = U[4 * s];     pf.u[1] = U[4 * s + 1];
          pf.u[2] = R[s][0];      pf.u[3] = R[s][1];
        } else {
          pf.u[0] = R[s][0];      pf.u[1] = R[s][1];
          pf.u[2] = U[4 * s + 2]; pf.u[3] = U[4 * s + 3];
        }
        const int ks2 = tt * 2 + s;
#pragma unroll
        for (int dt = 0; dt < 2; ++dt) {
          bf16x8 vf = *(const bf16x8*)(Vc + ((ks2 & 1) ? off[dt][2 + (ks2 >> 1)]
                                                       : off[dt][ks2 >> 1]));
          // NOTE: off[dt][ks2] == drow*64 + (((ks2*2+h)^(drow&7))<<3); rebuild directly:
          (void)vf;
          bf16x8 vf2 = *(const bf16x8*)(Vc + (dt * 32 + l31) * 64 +
                                        (((ks2 * 2 + h) ^ ((dt * 32 + l31) & 7)) << 3));
          o[dt] = __builtin_amdgcn_mfma_f32_32x32x16_bf16(vf2, pf.v, o[dt], 0, 0, 0);
        }
      }
    }
    __syncthreads();
  }

  // epilogue: O^T (lane: q=l31, rows=d) -> LDS -> coalesced [q][d] f32 stores
  const float linv = 1.f / lrow;
#pragma unroll
  for (int dt = 0; dt < 2; ++dt)
#pragma unroll
    for (int r = 0; r < 16; ++r) {
      const int d = dt * 32 + (r & 3) + 8 * (r >> 2) + 4 * h;
      Lbuf[d * 129 + wave * 32 + l31] = o[dt][r] * linv;
    }
  __syncthreads();
  {
    const int qloc = t >> 1, dh = (t & 1) * 32;
    float* ob = Out + (size_t)bh * 65536 + (size_t)(qb * 128 + qloc) * 64 + dh;
#pragma unroll
    for (int c = 0; c < 8; ++c) {
      float4 v = { Lbuf[(dh + 4 * c + 0) * 129 + qloc],
                   Lbuf[(dh + 4 * c + 1) * 129 + qloc],
                   Lbuf[(dh + 4 * c + 2) * 129 + qloc],
                   Lbuf[(dh + 4 * c + 3) * 129 + qloc] };
      *(float4*)(ob + 4 * c) = v;
    }
  }
}

// ---------------- launch ----------------
extern "C" void kernel_launch(void* const* d_in, const int* in_sizes, int n_in,
                              void* d_out, int out_size, void* d_ws, size_t ws_size,
                              hipStream_t stream) {
  (void)in_sizes; (void)n_in; (void)out_size; (void)ws_size;
  const float* x  = (const float*)d_in[0];
  const float* Wq = (const float*)d_in[1];
  const float* bq = (const float*)d_in[2];
  const float* Wk = (const float*)d_in[3];
  const float* bk = (const float*)d_in[4];
  const float* Wv = (const float*)d_in[5];
  const float* bv = (const float*)d_in[6];

  // ws layout (bytes): Xb/VT[32M] | Wb[1.5M] | QKV[96M]
  // Xb is dead after the GEMM; VT reuses its region.
  ushort* Xb  = (ushort*)d_ws;
  ushort* VT  = (ushort*)d_ws;
  ushort* Wb  = (ushort*)((char*)d_ws + 33554432);
  ushort* QKV = (ushort*)((char*)d_ws + 35127296);
  ushort* Vn  = QKV + 2 * (size_t)M_ROWS * 512;   // natural V plane

  cvt_all_kernel<<<2432, 256, 0, stream>>>(x, Wq, Wk, Wv, Xb, Wb);

  qkv_gemm_kernel<<<256 * 12, 256, 0, stream>>>(Xb, Wb, bq, bk, bv, QKV);

  vtrans_kernel<<<1024, 256, 0, stream>>>(Vn, VT);

  attn_kernel<<<256 * 8, 256, 0, stream>>>(QKV, VT, (float*)d_out);
}

// Round 7
// 235.599 us; speedup vs baseline: 1.7952x; 1.0558x over previous
//
#include <hip/hip_runtime.h>
#include <hip/hip_bf16.h>
#include <stdint.h>

#define AS_G __attribute__((address_space(1)))
#define AS_L __attribute__((address_space(3)))

typedef short bf16x8 __attribute__((ext_vector_type(8)));   // bits of 8 bf16
typedef float f32x4  __attribute__((ext_vector_type(4)));
typedef float f32x16 __attribute__((ext_vector_type(16)));
typedef unsigned int u32x2 __attribute__((ext_vector_type(2)));

// Problem constants (B=32, N=1024, D=512, H=8, DH=64)
constexpr int   M_ROWS = 32768;                    // B*N
constexpr float QSCALE = 0.18033688011112042f;     // log2(e) / sqrt(64)

__device__ __forceinline__ ushort f2bf(float f) {  // hw RTNE f32->bf16
  union { __hip_bfloat16 h; ushort u; } c;
  c.h = __float2bfloat16(f);
  return c.u;
}
__device__ __forceinline__ uint32_t pack2bf(float lo, float hi) {
  union { __hip_bfloat162 b; uint32_t u; } r;
  r.b.x = __float2bfloat16(lo);
  r.b.y = __float2bfloat16(hi);
  return r.u;
}
// permlane32_swap(x,x): returns {dup_lo(x), dup_hi(x)} as an unordered set —
// used ONLY in symmetric reductions (fmax / +), correct under either
// dst/src row-order convention.
__device__ __forceinline__ u32x2 pswap(uint32_t x) {
  return __builtin_amdgcn_permlane32_swap(x, x, false, false);
}
__device__ __forceinline__ void gload16(const ushort* g, ushort* l) {
  // async global->LDS, 16B/lane; LDS dest must be uniform_base + lane*16
  __builtin_amdgcn_global_load_lds((const AS_G uint32_t*)g, (AS_L uint32_t*)l, 16, 0, 0);
}

// ---------------- f32 -> bf16 convert (x + 3 W in one launch) ----------------
__device__ __forceinline__ void cvt8(const float* __restrict__ in,
                                     ushort* __restrict__ out, int i) {
  float4 a = reinterpret_cast<const float4*>(in)[2 * i];
  float4 b = reinterpret_cast<const float4*>(in)[2 * i + 1];
  ushort4 o0 = {f2bf(a.x), f2bf(a.y), f2bf(a.z), f2bf(a.w)};
  ushort4 o1 = {f2bf(b.x), f2bf(b.y), f2bf(b.z), f2bf(b.w)};
  reinterpret_cast<ushort4*>(out)[2 * i]     = o0;
  reinterpret_cast<ushort4*>(out)[2 * i + 1] = o1;
}

__global__ __launch_bounds__(256) void cvt_all_kernel(
    const float* __restrict__ x,  const float* __restrict__ wq,
    const float* __restrict__ wk, const float* __restrict__ wv,
    ushort* __restrict__ xb, ushort* __restrict__ wb) {
  const int b = blockIdx.x, t = threadIdx.x;
  if (b < 2048) {                 // x: 2,097,152 groups = 2048*256*4
    const int i0 = b * 256 + t;
#pragma unroll
    for (int rep = 0; rep < 4; ++rep) cvt8(x, xb, i0 + rep * 524288);
  } else {                        // W: 3 mats x 32768 groups (128 blocks each)
    const int c = b - 2048, m = c >> 7;
    const float* src = (m == 0) ? wq : (m == 1 ? wk : wv);
    cvt8(src, wb + m * 262144, (c & 127) * 256 + t);
  }
}

// ---------------- QKV projection GEMM (known-good) ----------------
// C = X @ W^T + bias -> bf16 plane [32768][512]; Q pre-scaled by QSCALE.
__global__ __launch_bounds__(256) void qkv_gemm_kernel(
    const ushort* __restrict__ Xb, const ushort* __restrict__ Wall,
    const float* __restrict__ bq, const float* __restrict__ bk,
    const float* __restrict__ bv,
    ushort* __restrict__ QKV)
{
  __shared__ ushort As[128 * 64];
  __shared__ ushort Bs[128 * 64];

  const int tile = blockIdx.x;
  const int mt  = tile & 255;
  const int cz  = tile >> 8;     // 0..11
  const int mat = cz >> 2;       // 0:q 1:k 2:v
  const int nt  = cz & 3;

  const ushort* W    = Wall + (size_t)mat * (512 * 512);
  const float*  bias = (mat == 0) ? bq : (mat == 1 ? bk : bv);
  ushort*       Out  = QKV + (size_t)mat * ((size_t)M_ROWS * 512);
  const float   oscale = (mat == 0) ? QSCALE : 1.0f;

  const int m0 = mt * 128, n0 = nt * 128;
  const int t = threadIdx.x, lane = t & 63, wave = t >> 6;
  const int wr = wave >> 1, wc = wave & 1;
  const int l15 = lane & 15, lg = lane >> 4;

  f32x4 acc[4][4];
#pragma unroll
  for (int i = 0; i < 4; i++)
#pragma unroll
    for (int j = 0; j < 4; j++) acc[i][j] = {0.f, 0.f, 0.f, 0.f};

  for (int kt = 0; kt < 8; ++kt) {
    const int k0 = kt * 64;
    __syncthreads();
#pragma unroll
    for (int i = 0; i < 4; ++i) {
      int c = i * 256 + t, row = c >> 3, col8 = (c & 7) * 8;
      gload16(Xb + (size_t)(m0 + row) * 512 + k0 + col8, As + c * 8);
    }
#pragma unroll
    for (int i = 0; i < 4; ++i) {
      int c = i * 256 + t, row = c >> 3, col8 = (c & 7) * 8;
      gload16(W + (size_t)(n0 + row) * 512 + k0 + col8, Bs + c * 8);
    }
    __syncthreads();
#pragma unroll
    for (int ks = 0; ks < 2; ++ks) {
      bf16x8 af[4], bfr[4];
#pragma unroll
      for (int i = 0; i < 4; ++i) {
        af[i]  = *(const bf16x8*)(As + (wr * 64 + i * 16 + l15) * 64 + ks * 32 + lg * 8);
        bfr[i] = *(const bf16x8*)(Bs + (wc * 64 + i * 16 + l15) * 64 + ks * 32 + lg * 8);
      }
#pragma unroll
      for (int i = 0; i < 4; ++i)
#pragma unroll
        for (int j = 0; j < 4; ++j)
          acc[i][j] = __builtin_amdgcn_mfma_f32_16x16x32_bf16(af[i], bfr[j], acc[i][j], 0, 0, 0);
    }
  }
#pragma unroll
  for (int j = 0; j < 4; ++j) {
    const int col = n0 + wc * 64 + j * 16 + l15;
    const float bc = bias[col];
#pragma unroll
    for (int i = 0; i < 4; ++i) {
      const int row0 = m0 + wr * 64 + i * 16 + lg * 4;
#pragma unroll
      for (int r = 0; r < 4; ++r)
        Out[(size_t)(row0 + r) * 512 + col] = f2bf((acc[i][j][r] + bc) * oscale);
    }
  }
}

// ---------------- V transpose + key permutation --------------------------
// VT'[bh][dh][n64*64 + p] = flatV[bh*65536 + (n64*64 + pi(p))*64 + dh]
// pi(p): with p = tt*32 + s*16 + h*8 + j  ->  tt*32 + 16s + 4h + (j&3) + 8*(j>>2).
// This matches the MFMA C-layout crow() of the swapped QK^T, so the attention
// PV B-fragment needs NO cross-lane exchange.
__global__ __launch_bounds__(256) void vtrans_kernel(
    const ushort* __restrict__ Vn, ushort* __restrict__ VT)
{
  __shared__ ushort T[64][258];   // [dh][n-local], padded stride
  const int bh = blockIdx.x >> 2, nc = blockIdx.x & 3;
  const ushort* src = Vn + (size_t)bh * 65536 + nc * 16384;
  ushort* dst = VT + (size_t)bh * 65536 + nc * 256;
  const int t = threadIdx.x;
#pragma unroll
  for (int i = 0; i < 8; ++i) {   // load [256 n][64 dh], scatter-transpose
    int c = i * 256 + t, n = c >> 3, col8 = (c & 7) * 8;
    ushort tmp[8];
    *(int4*)tmp = *(const int4*)(src + n * 64 + col8);
#pragma unroll
    for (int j = 0; j < 8; ++j) T[col8 + j][n] = tmp[j];
  }
  __syncthreads();
#pragma unroll
  for (int i = 0; i < 8; ++i) {   // write [64 dh][256 n] coalesced, pi-gathered
    int c = i * 256 + t, dh = c >> 5, a8 = (c & 31) * 8;
    const int w = a8 & 63;        // position of this 8-group within its 64-tile
    const int pbase = (a8 & 192) + (w >> 5) * 32 + ((w >> 4) & 1) * 16
                    + ((w >> 3) & 1) * 4;
    ushort tmp[8];
    *(uint64_t*)(tmp)     = *(const uint64_t*)(&T[dh][pbase]);      // j=0..3
    *(uint64_t*)(tmp + 4) = *(const uint64_t*)(&T[dh][pbase + 8]);  // j=4..7
    *(int4*)(dst + (size_t)dh * 1024 + a8) = *(const int4*)tmp;
  }
}

// ---------------- flash attention: 4 waves x 32 q-rows, KVBLK=64, 32x32x16 ----
// Swapped QK^T (S^T = K Q^T) -> lane-local softmax; V key-permuted so the PV
// B-fragment is the lane's own packed P values (no cross-lane exchange).
// PV as O^T = V^T P^T. XCD-chunked block swizzle for K/V L2 reuse.
__global__ __launch_bounds__(256, 4) void attn_kernel(
    const ushort* __restrict__ QKV,   // planes: Q[bh][n][64], K[bh][n][64]
    const ushort* __restrict__ VTg_,  // V^T [bh][64 dh][1024 n], key-permuted
    float* __restrict__ Out)          // [bh][1024][64] f32
{
  constexpr int PLANE = M_ROWS * 512;
  __shared__ ushort SMEM[64 * 258];          // 33024 B: staging + out-transpose
  ushort* sK = SMEM;                          // [2][4096]
  ushort* sV = SMEM + 8192;                   // [2][4096]
  float* Lbuf = (float*)SMEM;                 // epilogue alias [64][129]

  const int raw = blockIdx.x;                 // 2048 = 8 XCD chunks x 256
  const int blk = ((raw & 7) << 8) | (raw >> 3);
  const int bh = blk >> 3, qb = blk & 7;
  const ushort* Qg  = QKV + (size_t)bh * 65536;
  const ushort* Kg  = QKV + (size_t)PLANE + (size_t)bh * 65536;
  const ushort* Vtg = VTg_ + (size_t)bh * 65536;

  const int t = threadIdx.x, lane = t & 63, wave = t >> 6;
  const int l31 = lane & 31, h = lane >> 5;
  const int q = qb * 128 + wave * 32 + l31;

  bf16x8 qf[4];
#pragma unroll
  for (int ks = 0; ks < 4; ++ks)
    qf[ks] = *(const bf16x8*)(Qg + (size_t)q * 64 + ks * 16 + h * 8);

  float mrow = -1e30f, lrow = 0.f;
  f32x16 o[2];
#pragma unroll
  for (int r = 0; r < 16; ++r) { o[0][r] = 0.f; o[1][r] = 0.f; }

  // prologue stage (tile 0)
#pragma unroll
  for (int i = 0; i < 2; ++i) {
    int c = i * 256 + t, row = c >> 3, slot = c & 7;
    gload16(Kg + (size_t)row * 64 + ((slot ^ (row & 7)) << 3), sK + c * 8);
    gload16(Vtg + (size_t)row * 1024 + ((slot ^ (row & 7)) << 3), sV + c * 8);
  }
  __syncthreads();

  for (int kv = 0; kv < 16; ++kv) {
    const int cur = kv & 1;
    if (kv < 15) {
      const int nx = cur ^ 1, kn = kv + 1;
#pragma unroll
      for (int i = 0; i < 2; ++i) {
        int c = i * 256 + t, row = c >> 3, slot = c & 7;
        gload16(Kg + (size_t)(kn * 64 + row) * 64 + ((slot ^ (row & 7)) << 3),
                sK + nx * 4096 + c * 8);
        gload16(Vtg + (size_t)row * 1024 + kn * 64 + ((slot ^ (row & 7)) << 3),
                sV + nx * 4096 + c * 8);
      }
    }
    const ushort* Kc = sK + cur * 4096;
    const ushort* Vc = sV + cur * 4096;

    // S^T = K Q^T : lane holds S[k = tt*32 + (r&3)+8*(r>>2)+4h][q = l31]
    f32x16 st[2];
#pragma unroll
    for (int tt = 0; tt < 2; ++tt) {
      f32x16 a;
#pragma unroll
      for (int r = 0; r < 16; ++r) a[r] = 0.f;
      __builtin_amdgcn_s_setprio(1);
#pragma unroll
      for (int ks = 0; ks < 4; ++ks) {
        const int krow = tt * 32 + l31;
        bf16x8 kf = *(const bf16x8*)(Kc + krow * 64 + (((ks * 2 + h) ^ (krow & 7)) << 3));
        a = __builtin_amdgcn_mfma_f32_32x32x16_bf16(kf, qf[ks], a, 0, 0, 0);
      }
      __builtin_amdgcn_s_setprio(0);
      st[tt] = a;
    }

    // online softmax (row = q = l31): tree max, cross-half via permlane (symmetric)
    float mx;
    {
      float t8[8];
#pragma unroll
      for (int i = 0; i < 8; ++i)
        t8[i] = fmaxf(fmaxf(st[0][i], st[0][i + 8]), fmaxf(st[1][i], st[1][i + 8]));
      float a0 = fmaxf(fmaxf(t8[0], t8[1]), fmaxf(t8[2], t8[3]));
      float a1 = fmaxf(fmaxf(t8[4], t8[5]), fmaxf(t8[6], t8[7]));
      mx = fmaxf(a0, a1);
    }
    {
      u32x2 d = pswap(__float_as_uint(mx));
      mx = fmaxf(__uint_as_float(d.x), __uint_as_float(d.y));
    }
    if (!__all(mx - mrow <= 8.0f)) {       // defer-max: rescale rare after t0
      const float mnew = fmaxf(mrow, mx);
      const float alpha = exp2f(mrow - mnew);
      mrow = mnew;
      lrow *= alpha;
#pragma unroll
      for (int r = 0; r < 16; ++r) { o[0][r] *= alpha; o[1][r] *= alpha; }
    }
#pragma unroll
    for (int tt = 0; tt < 2; ++tt)
#pragma unroll
      for (int r = 0; r < 16; ++r) st[tt][r] = exp2f(st[tt][r] - mrow);
    {
      float s8[8];
#pragma unroll
      for (int i = 0; i < 8; ++i)
        s8[i] = (st[0][i] + st[0][i + 8]) + (st[1][i] + st[1][i + 8]);
      float rs = ((s8[0] + s8[1]) + (s8[2] + s8[3]))
               + ((s8[4] + s8[5]) + (s8[6] + s8[7]));
      u32x2 d = pswap(__float_as_uint(rs));
      lrow += __uint_as_float(d.x) + __uint_as_float(d.y);
    }

    // O^T += V'^T P'^T : V key-permuted so pf = own packed st values.
    // k-slot (tt,s,h,j) corresponds to original key tt*32+16s+4h+(j&3)+8*(j>>2)
    // = crow(8s+j', h) — exactly what st[tt][8s+...] holds.
#pragma unroll
    for (int tt = 0; tt < 2; ++tt) {
#pragma unroll
      for (int s = 0; s < 2; ++s) {
        union { uint32_t u[4]; bf16x8 v; } pf;
#pragma unroll
        for (int i = 0; i < 4; ++i)
          pf.u[i] = pack2bf(st[tt][8 * s + 2 * i], st[tt][8 * s + 2 * i + 1]);
        const int ks2 = tt * 2 + s;
        __builtin_amdgcn_s_setprio(1);
#pragma unroll
        for (int dt = 0; dt < 2; ++dt) {
          const int drow = dt * 32 + l31;
          bf16x8 vf = *(const bf16x8*)(Vc + drow * 64 +
                                       (((ks2 * 2 + h) ^ (drow & 7)) << 3));
          o[dt] = __builtin_amdgcn_mfma_f32_32x32x16_bf16(vf, pf.v, o[dt], 0, 0, 0);
        }
        __builtin_amdgcn_s_setprio(0);
      }
    }
    __syncthreads();
  }

  // epilogue: O^T (lane: q=l31, rows=d) -> LDS -> coalesced [q][d] f32 stores
  const float linv = 1.f / lrow;
#pragma unroll
  for (int dt = 0; dt < 2; ++dt)
#pragma unroll
    for (int r = 0; r < 16; ++r) {
      const int d = dt * 32 + (r & 3) + 8 * (r >> 2) + 4 * h;
      Lbuf[d * 129 + wave * 32 + l31] = o[dt][r] * linv;
    }
  __syncthreads();
  {
    const int qloc = t >> 1, dh = (t & 1) * 32;
    float* ob = Out + (size_t)bh * 65536 + (size_t)(qb * 128 + qloc) * 64 + dh;
#pragma unroll
    for (int c = 0; c < 8; ++c) {
      float4 v = { Lbuf[(dh + 4 * c + 0) * 129 + qloc],
                   Lbuf[(dh + 4 * c + 1) * 129 + qloc],
                   Lbuf[(dh + 4 * c + 2) * 129 + qloc],
                   Lbuf[(dh + 4 * c + 3) * 129 + qloc] };
      *(float4*)(ob + 4 * c) = v;
    }
  }
}

// ---------------- launch ----------------
extern "C" void kernel_launch(void* const* d_in, const int* in_sizes, int n_in,
                              void* d_out, int out_size, void* d_ws, size_t ws_size,
                              hipStream_t stream) {
  (void)in_sizes; (void)n_in; (void)out_size; (void)ws_size;
  const float* x  = (const float*)d_in[0];
  const float* Wq = (const float*)d_in[1];
  const float* bq = (const float*)d_in[2];
  const float* Wk = (const float*)d_in[3];
  const float* bk = (const float*)d_in[4];
  const float* Wv = (const float*)d_in[5];
  const float* bv = (const float*)d_in[6];

  // ws layout (bytes): Xb/VT[32M] | Wb[1.5M] | QKV[96M]
  // Xb is dead after the GEMM; VT reuses its region.
  ushort* Xb  = (ushort*)d_ws;
  ushort* VT  = (ushort*)d_ws;
  ushort* Wb  = (ushort*)((char*)d_ws + 33554432);
  ushort* QKV = (ushort*)((char*)d_ws + 35127296);
  ushort* Vn  = QKV + 2 * (size_t)M_ROWS * 512;   // natural V plane

  cvt_all_kernel<<<2432, 256, 0, stream>>>(x, Wq, Wk, Wv, Xb, Wb);

  qkv_gemm_kernel<<<256 * 12, 256, 0, stream>>>(Xb, Wb, bq, bk, bv, QKV);

  vtrans_kernel<<<1024, 256, 0, stream>>>(Vn, VT);

  attn_kernel<<<256 * 8, 256, 0, stream>>>(QKV, VT, (float*)d_out);
}